// Round 1
// baseline (87.664 us; speedup 1.0000x reference)
//
#include <hip/hip_runtime.h>
#include <math.h>

// diag-RTRL fused kernel for MI355X (gfx950)
//   s      = tanh(0.9*u + x@W)         [32,1024]
//   u_new  = 0.9*u + x@W               [32,1024]
//   E_new  = 0.9*E + x[:,:,None]       [32,1024,1024]  <-- 268 MB stream, dominates
//
// Single fused launch: blocks [0,GEMM_BLOCKS) compute the small GEMM + tanh,
// blocks [GEMM_BLOCKS, ...) stream E with float4. GEMM overlaps under the
// memory-bound E stream instead of serializing after it.

#define BETA 0.9f

constexpr int Bb   = 32;
constexpr int D_IN = 1024;
constexpr int D_H  = 1024;

constexpr int THREADS     = 256;
constexpr int GEMM_BLOCKS = 128;   // one thread per (b,j) output: 32*1024/256
constexpr int E_BLOCKS    = 2048;  // grid-stride over 8,388,608 float4

__global__ __launch_bounds__(THREADS) void diag_rtrl_fused(
    const float* __restrict__ x,   // [32,1024]
    const float* __restrict__ W,   // [1024,1024]
    const float* __restrict__ u,   // [32,1024]
    const float* __restrict__ E,   // [32,1024,1024]
    float* __restrict__ out)       // [s | u_new | E_new]
{
    const int blk = blockIdx.x;

    if (blk < GEMM_BLOCKS) {
        // ---- GEMM + tanh: one thread per output element (b,j) ----
        const int t = blk * THREADS + threadIdx.x;   // t in [0, 32768)
        const int b = t >> 10;                       // t / 1024
        const int j = t & 1023;                      // t % 1024

        const float* xr = x + b * D_IN;
        float acc = 0.0f;
        #pragma unroll 8
        for (int i = 0; i < D_IN; ++i) {
            acc = fmaf(xr[i], W[i * D_H + j], acc);  // W read coalesced over j
        }
        const float un = BETA * u[t] + acc;
        out[t]                 = tanhf(un);          // s
        out[Bb * D_H + t]      = un;                 // u_new
    } else {
        // ---- E stream: E_new = 0.9*E + x[b,i], vectorized float4 ----
        const float4* __restrict__ E4 = (const float4*)E;
        float4* __restrict__ O4 = (float4*)(out + 2 * Bb * D_H);

        const int nvec   = (Bb * D_IN * D_H) / 4;    // 8,388,608
        const int stride = E_BLOCKS * THREADS;       // 524,288
        int v = (blk - GEMM_BLOCKS) * THREADS + threadIdx.x;

        for (; v < nvec; v += stride) {
            // 256 consecutive float4 share one (b,i) -> x index = v >> 8
            const float xv = x[v >> 8];
            float4 e = E4[v];
            float4 o;
            o.x = fmaf(BETA, e.x, xv);
            o.y = fmaf(BETA, e.y, xv);
            o.z = fmaf(BETA, e.z, xv);
            o.w = fmaf(BETA, e.w, xv);
            O4[v] = o;
        }
    }
}

extern "C" void kernel_launch(void* const* d_in, const int* in_sizes, int n_in,
                              void* d_out, int out_size, void* d_ws, size_t ws_size,
                              hipStream_t stream) {
    const float* x = (const float*)d_in[0];
    const float* W = (const float*)d_in[1];
    const float* u = (const float*)d_in[2];
    const float* E = (const float*)d_in[3];
    float* out = (float*)d_out;

    const int grid = GEMM_BLOCKS + E_BLOCKS;
    diag_rtrl_fused<<<grid, THREADS, 0, stream>>>(x, W, u, E, out);
}

// Round 2
// 62.762 us; speedup vs baseline: 1.3968x; 1.3968x over previous
//
#include <hip/hip_runtime.h>
#include <math.h>

// diag-RTRL fused kernel for MI355X (gfx950)
//   s      = tanh(0.9*u + x@W)         [32,1024]
//   u_new  = 0.9*u + x@W               [32,1024]
//   E_new  = 0.9*E + x[:,:,None]       [32,1024,1024]  <-- 268 MB stream, dominates
//
// Round-2 changes vs round-1:
//  * GEMM blocks: x-row staged in LDS (b is block-uniform), 4 independent
//    accumulator chains + unroll -> ~16 W loads in flight. Kills the
//    latency-bound tail that made round 1 take 87 us (Occupancy 39%,
//    VALUBusy 4.5% = idle tail).
//  * E-stream: non-temporal stores for out so the 134 MB of output writes
//    don't evict E from the 256 MB L3 (round-1 FETCH_SIZE=70MB showed E is
//    already ~half L3-resident across replays; NT stores improve that).

#define BETA 0.9f

constexpr int Bb   = 32;
constexpr int D_IN = 1024;
constexpr int D_H  = 1024;

constexpr int THREADS     = 256;
constexpr int GEMM_BLOCKS = 128;   // 4 blocks per batch row: 256 j-columns each
constexpr int E_BLOCKS    = 2048;  // grid-stride over 8,388,608 float4

typedef float f4 __attribute__((ext_vector_type(4)));

__global__ __launch_bounds__(THREADS) void diag_rtrl_fused(
    const float* __restrict__ x,   // [32,1024]
    const float* __restrict__ W,   // [1024,1024]
    const float* __restrict__ u,   // [32,1024]
    const float* __restrict__ E,   // [32,1024,1024]
    float* __restrict__ out)       // [s | u_new | E_new]
{
    const int blk = blockIdx.x;

    if (blk < GEMM_BLOCKS) {
        // ---- GEMM + tanh ----
        // block covers batch b = blk/4, columns j in [(blk%4)*256, +256)
        __shared__ float xs[D_IN];
        const int b     = blk >> 2;
        const int jbase = (blk & 3) * 256;

        // cooperative load of the x row (4 KB)
        for (int i = threadIdx.x; i < D_IN; i += THREADS)
            xs[i] = x[b * D_IN + i];
        __syncthreads();

        const int j = jbase + threadIdx.x;
        const float* __restrict__ Wp = W + j;

        float a0 = 0.f, a1 = 0.f, a2 = 0.f, a3 = 0.f;
        #pragma unroll 4
        for (int i = 0; i < D_IN; i += 4) {
            a0 = fmaf(xs[i + 0], Wp[(i + 0) << 10], a0);
            a1 = fmaf(xs[i + 1], Wp[(i + 1) << 10], a1);
            a2 = fmaf(xs[i + 2], Wp[(i + 2) << 10], a2);
            a3 = fmaf(xs[i + 3], Wp[(i + 3) << 10], a3);
        }
        const float acc = (a0 + a1) + (a2 + a3);

        const int t  = b * D_H + j;
        const float un = BETA * u[t] + acc;
        out[t]            = tanhf(un);   // s
        out[Bb * D_H + t] = un;          // u_new
    } else {
        // ---- E stream: E_new = 0.9*E + x[b,i], float4 + NT stores ----
        const f4* __restrict__ E4 = (const f4*)E;
        f4* __restrict__ O4 = (f4*)(out + 2 * Bb * D_H);

        const int nvec   = (Bb * D_IN * D_H) / 4;    // 8,388,608
        const int stride = E_BLOCKS * THREADS;       // 524,288
        int v = (blk - GEMM_BLOCKS) * THREADS + threadIdx.x;

        for (; v < nvec; v += stride) {
            // 256 consecutive float4 share one (b,i) -> x index = v >> 8
            const float xv = x[v >> 8];
            f4 e = E4[v];
            f4 o = e * BETA + xv;
            __builtin_nontemporal_store(o, &O4[v]);
        }
    }
}

extern "C" void kernel_launch(void* const* d_in, const int* in_sizes, int n_in,
                              void* d_out, int out_size, void* d_ws, size_t ws_size,
                              hipStream_t stream) {
    const float* x = (const float*)d_in[0];
    const float* W = (const float*)d_in[1];
    const float* u = (const float*)d_in[2];
    const float* E = (const float*)d_in[3];
    float* out = (float*)d_out;

    const int grid = GEMM_BLOCKS + E_BLOCKS;
    diag_rtrl_fused<<<grid, THREADS, 0, stream>>>(x, W, u, E, out);
}